// Round 1
// baseline (1885.719 us; speedup 1.0000x reference)
//
#include <hip/hip_runtime.h>
#include <stdint.h>

// Problem constants (dense MoE: router_indices UNUSED by the reference)
#define NE 32
#define ND 2048
#define NF 768
#define NT 2048
#define NEF (NE * NF)   // 24576

// Tile config
#define BM 128
#define BN 64
#define BK 32
#define BSTR 40   // LDS B-row stride in bf16 elems (80B) -> conflict-free writes & reads

typedef __attribute__((ext_vector_type(8))) short short8;
typedef __attribute__((ext_vector_type(4))) float floatx4;

__device__ __forceinline__ unsigned pk_bf16(float a, float b) {
  union { float f; unsigned u; } ua, ub;
  ua.f = a; ub.f = b;
  unsigned ra = (ua.u + 0x7fffu + ((ua.u >> 16) & 1u)) >> 16;
  unsigned rb = (ub.u + 0x7fffu + ((ub.u >> 16) & 1u)) & 0xffff0000u;
  return ra | rb;
}
__device__ __forceinline__ unsigned short bf16_1(float a) {
  union { float f; unsigned u; } ua; ua.f = a;
  return (unsigned short)((ua.u + 0x7fffu + ((ua.u >> 16) & 1u)) >> 16);
}

#define GLOAD_LDS16(g, l)                                                     \
  __builtin_amdgcn_global_load_lds(                                           \
      (const __attribute__((address_space(1))) void*)(g),                     \
      (__attribute__((address_space(3))) void*)(l), 16, 0, 0)

// ---------------------------------------------------------------- X -> bf16
__global__ void k_cvt_x(const float* __restrict__ x, unsigned short* __restrict__ xb, int n4) {
  int i = blockIdx.x * blockDim.x + threadIdx.x;
  if (i < n4) {
    float4 v = ((const float4*)x)[i];
    uint2 o;
    o.x = pk_bf16(v.x, v.y);
    o.y = pk_bf16(v.z, v.w);
    ((uint2*)xb)[i] = o;
  }
}

// ------------------------------------------------- Phase A: X@W1 + silu-gate
// grid: (16 mtiles * 12 ntiles, 32 experts), 256 threads
__global__ __launch_bounds__(256, 2) void k_gemm1(
    const unsigned short* __restrict__ xb,  // NT x ND bf16
    const float* __restrict__ w1,           // NE x ND x 2NF fp32
    const float* __restrict__ rw,           // NT x NE fp32
    unsigned short* __restrict__ gws)       // NT x NEF bf16 (gated')
{
  __shared__ unsigned short sA[BM * BK];     // [m][k], 64B rows
  __shared__ unsigned short sG[BN * BSTR];   // [n][k], 80B rows (gate)
  __shared__ unsigned short sU[BN * BSTR];   // [n][k] (up)
  __shared__ float srw[BM];

  const int e   = blockIdx.y;
  const int mt  = blockIdx.x & 15;        // mtile fastest -> W1-tile sharers adjacent
  const int nt  = blockIdx.x >> 4;        // 0..11
  const int m0  = mt * BM, n0 = nt * BN;
  const int tid = threadIdx.x;
  const int wid = tid >> 6, lane = tid & 63;
  const int wm = wid >> 1, wn = wid & 1;
  const int l15 = lane & 15, q = lane >> 4;

  if (tid < BM) srw[tid] = rw[(size_t)(m0 + tid) * NE + e];

  const float* w1e = w1 + (size_t)e * ND * (2 * NF);

  floatx4 accG[4][2], accU[4][2];
#pragma unroll
  for (int i = 0; i < 4; i++)
#pragma unroll
    for (int j = 0; j < 2; j++) {
      accG[i][j] = (floatx4){0.f, 0.f, 0.f, 0.f};
      accU[i][j] = (floatx4){0.f, 0.f, 0.f, 0.f};
    }

  // A staging: wave stages rows [wid*32, wid*32+32), 2 x global_load_lds(16B)
  const int arow = wid * 32 + (lane >> 2);
  const int akoff = (lane & 3) * 8;
  const unsigned short* aptr = xb + (size_t)(m0 + arow) * ND + akoff;
  unsigned short* aLds = &sA[wid * 32 * BK];  // wave-uniform

  // B staging: wave handles k-group [wid*8, wid*8+8), lane = column
  const float* gptr0 = w1e + (size_t)(wid * 8) * (2 * NF) + n0 + lane;

  for (int kb = 0; kb < ND / BK; ++kb) {
    const unsigned short* ap = aptr + kb * BK;
    const float* gp = gptr0 + (size_t)kb * BK * (2 * NF);
    float gv[8], uv[8];
#pragma unroll
    for (int r = 0; r < 8; r++) {
      gv[r] = gp[(size_t)r * (2 * NF)];
      uv[r] = gp[(size_t)r * (2 * NF) + NF];
    }

    __syncthreads();  // prior iteration's LDS reads done

    GLOAD_LDS16(ap, aLds);
    GLOAD_LDS16(ap + 16 * ND, aLds + 16 * BK);

    uint4 wg, wu;
    wg.x = pk_bf16(gv[0], gv[1]); wg.y = pk_bf16(gv[2], gv[3]);
    wg.z = pk_bf16(gv[4], gv[5]); wg.w = pk_bf16(gv[6], gv[7]);
    wu.x = pk_bf16(uv[0], uv[1]); wu.y = pk_bf16(uv[2], uv[3]);
    wu.z = pk_bf16(uv[4], uv[5]); wu.w = pk_bf16(uv[6], uv[7]);
    *((uint4*)&sG[lane * BSTR + wid * 8]) = wg;
    *((uint4*)&sU[lane * BSTR + wid * 8]) = wu;

    __syncthreads();  // staging visible (vmcnt drained by barrier semantics)

    short8 bg0 = *(const short8*)&sG[(wn * 32 + 0  + l15) * BSTR + q * 8];
    short8 bg1 = *(const short8*)&sG[(wn * 32 + 16 + l15) * BSTR + q * 8];
    short8 bu0 = *(const short8*)&sU[(wn * 32 + 0  + l15) * BSTR + q * 8];
    short8 bu1 = *(const short8*)&sU[(wn * 32 + 16 + l15) * BSTR + q * 8];
#pragma unroll
    for (int i = 0; i < 4; i++) {
      short8 af = *(const short8*)&sA[(wm * 64 + i * 16 + l15) * BK + q * 8];
      accG[i][0] = __builtin_amdgcn_mfma_f32_16x16x32_bf16(af, bg0, accG[i][0], 0, 0, 0);
      accG[i][1] = __builtin_amdgcn_mfma_f32_16x16x32_bf16(af, bg1, accG[i][1], 0, 0, 0);
      accU[i][0] = __builtin_amdgcn_mfma_f32_16x16x32_bf16(af, bu0, accU[i][0], 0, 0, 0);
      accU[i][1] = __builtin_amdgcn_mfma_f32_16x16x32_bf16(af, bu1, accU[i][1], 0, 0, 0);
    }
  }

  // Epilogue: gated' = up * silu(gate) * rw, store bf16
  const size_t obase = (size_t)m0 * NEF + (size_t)e * NF + n0 + wn * 32;
#pragma unroll
  for (int i = 0; i < 4; i++)
#pragma unroll
    for (int j = 0; j < 2; j++)
#pragma unroll
      for (int r = 0; r < 4; r++) {
        int row = wm * 64 + i * 16 + q * 4 + r;
        float g = accG[i][j][r];
        float u = accU[i][j][r];
        float sig = __builtin_amdgcn_rcpf(1.f + __expf(-g));
        float val = u * g * sig * srw[row];
        gws[obase + (size_t)row * NEF + j * 16 + l15] = bf16_1(val);
      }
}

// ------------------------------------------- Phase B: gated' @ W2 -> output
// grid: 16 mtiles * 32 ntiles = 512 blocks, 256 threads
__global__ __launch_bounds__(256, 2) void k_gemm2(
    const unsigned short* __restrict__ gb,  // NT x NEF bf16
    const float* __restrict__ w2,           // NEF x ND fp32 ((E,F,D) flattened)
    float* __restrict__ out)                // NT x ND fp32
{
  __shared__ unsigned short sA[BM * BK];
  __shared__ unsigned short sB[BN * BSTR];

  const int mt = blockIdx.x & 15;
  const int nt = blockIdx.x >> 4;   // 0..31
  const int m0 = mt * BM, n0 = nt * BN;
  const int tid = threadIdx.x;
  const int wid = tid >> 6, lane = tid & 63;
  const int wm = wid >> 1, wn = wid & 1;
  const int l15 = lane & 15, q = lane >> 4;

  floatx4 acc[4][2];
#pragma unroll
  for (int i = 0; i < 4; i++)
#pragma unroll
    for (int j = 0; j < 2; j++) acc[i][j] = (floatx4){0.f, 0.f, 0.f, 0.f};

  const int arow = wid * 32 + (lane >> 2);
  const int akoff = (lane & 3) * 8;
  const unsigned short* aptr = gb + (size_t)(m0 + arow) * NEF + akoff;
  unsigned short* aLds = &sA[wid * 32 * BK];

  const float* bptr0 = w2 + (size_t)(wid * 8) * ND + n0 + lane;

  for (int kb = 0; kb < NEF / BK; ++kb) {
    const unsigned short* ap = aptr + kb * BK;
    const float* bp = bptr0 + (size_t)kb * BK * ND;
    float bv[8];
#pragma unroll
    for (int r = 0; r < 8; r++) bv[r] = bp[(size_t)r * ND];

    __syncthreads();

    GLOAD_LDS16(ap, aLds);
    GLOAD_LDS16(ap + 16 * NEF, aLds + 16 * BK);

    uint4 wb;
    wb.x = pk_bf16(bv[0], bv[1]); wb.y = pk_bf16(bv[2], bv[3]);
    wb.z = pk_bf16(bv[4], bv[5]); wb.w = pk_bf16(bv[6], bv[7]);
    *((uint4*)&sB[lane * BSTR + wid * 8]) = wb;

    __syncthreads();

    short8 b0 = *(const short8*)&sB[(wn * 32 + 0  + l15) * BSTR + q * 8];
    short8 b1 = *(const short8*)&sB[(wn * 32 + 16 + l15) * BSTR + q * 8];
#pragma unroll
    for (int i = 0; i < 4; i++) {
      short8 af = *(const short8*)&sA[(wm * 64 + i * 16 + l15) * BK + q * 8];
      acc[i][0] = __builtin_amdgcn_mfma_f32_16x16x32_bf16(af, b0, acc[i][0], 0, 0, 0);
      acc[i][1] = __builtin_amdgcn_mfma_f32_16x16x32_bf16(af, b1, acc[i][1], 0, 0, 0);
    }
  }

#pragma unroll
  for (int i = 0; i < 4; i++)
#pragma unroll
    for (int j = 0; j < 2; j++)
#pragma unroll
      for (int r = 0; r < 4; r++) {
        int row = wm * 64 + i * 16 + q * 4 + r;
        out[(size_t)(m0 + row) * ND + n0 + wn * 32 + j * 16 + l15] = acc[i][j][r];
      }
}

// ---------------------------------------------------------------------------
extern "C" void kernel_launch(void* const* d_in, const int* in_sizes, int n_in,
                              void* d_out, int out_size, void* d_ws, size_t ws_size,
                              hipStream_t stream) {
  const float* x  = (const float*)d_in[0];   // hidden_states (T,D)
  const float* rw = (const float*)d_in[1];   // routing_weights (T,E)
  // d_in[2] router_indices: unused by reference
  const float* w1 = (const float*)d_in[3];   // gate_up_proj (E,D,2F)
  const float* w2 = (const float*)d_in[4];   // down_proj (E,F,D)
  float* out = (float*)d_out;

  unsigned short* xb = (unsigned short*)d_ws;          // NT*ND bf16 (8 MB)
  unsigned short* gb = xb + (size_t)NT * ND;           // NT*NEF bf16 (100.7 MB)

  k_cvt_x<<<(NT * ND / 4 + 255) / 256, 256, 0, stream>>>(x, xb, NT * ND / 4);

  dim3 gA(16 * (NF / BN), NE);  // 192 x 32
  k_gemm1<<<gA, 256, 0, stream>>>(xb, w1, rw, gb);

  k_gemm2<<<16 * (ND / BN), 256, 0, stream>>>(gb, w2, out);
}

// Round 2
// 1674.535 us; speedup vs baseline: 1.1261x; 1.1261x over previous
//
#include <hip/hip_runtime.h>
#include <stdint.h>

// Problem constants (dense MoE: router_indices UNUSED by the reference)
#define NE 32
#define ND 2048
#define NF 768
#define NT 2048
#define NEF (NE * NF)   // 24576

// Tile config
#define BM 128
#define BN 64
#define BK 32
#define BSTR 40     // LDS B-row stride in bf16 elems (80B) -> conflict-free writes & reads
#define KSPLIT 4    // gemm2 K-split: 512 -> 2048 blocks (2 -> 8 blocks/CU)

typedef __attribute__((ext_vector_type(8))) short short8;
typedef __attribute__((ext_vector_type(4))) float floatx4;

__device__ __forceinline__ unsigned pk_bf16(float a, float b) {
  union { float f; unsigned u; } ua, ub;
  ua.f = a; ub.f = b;
  unsigned ra = (ua.u + 0x7fffu + ((ua.u >> 16) & 1u)) >> 16;
  unsigned rb = (ub.u + 0x7fffu + ((ub.u >> 16) & 1u)) & 0xffff0000u;
  return ra | rb;
}
__device__ __forceinline__ unsigned short bf16_1(float a) {
  union { float f; unsigned u; } ua; ua.f = a;
  return (unsigned short)((ua.u + 0x7fffu + ((ua.u >> 16) & 1u)) >> 16);
}

#define GLOAD_LDS16(g, l)                                                     \
  __builtin_amdgcn_global_load_lds(                                           \
      (const __attribute__((address_space(1))) void*)(g),                     \
      (__attribute__((address_space(3))) void*)(l), 16, 0, 0)

// ---------------------------------------------------------------- X -> bf16
__global__ void k_cvt_x(const float* __restrict__ x, unsigned short* __restrict__ xb, int n4) {
  int i = blockIdx.x * blockDim.x + threadIdx.x;
  if (i < n4) {
    float4 v = ((const float4*)x)[i];
    uint2 o;
    o.x = pk_bf16(v.x, v.y);
    o.y = pk_bf16(v.z, v.w);
    ((uint2*)xb)[i] = o;
  }
}

// ------------------------------------------------- Phase A: X@W1 + silu-gate
// grid: (16 mtiles * 12 ntiles, 32 experts), 256 threads
__global__ __launch_bounds__(256, 2) void k_gemm1(
    const unsigned short* __restrict__ xb,  // NT x ND bf16
    const float* __restrict__ w1,           // NE x ND x 2NF fp32
    const float* __restrict__ rw,           // NT x NE fp32
    unsigned short* __restrict__ gws)       // NT x NEF bf16 (gated')
{
  __shared__ unsigned short sA[BM * BK];     // [m][k], 64B rows
  __shared__ unsigned short sG[BN * BSTR];   // [n][k], 80B rows (gate)
  __shared__ unsigned short sU[BN * BSTR];   // [n][k] (up)
  __shared__ float srw[BM];

  const int e   = blockIdx.y;
  const int mt  = blockIdx.x & 15;        // mtile fastest -> W1-tile sharers adjacent
  const int nt  = blockIdx.x >> 4;        // 0..11
  const int m0  = mt * BM, n0 = nt * BN;
  const int tid = threadIdx.x;
  const int wid = tid >> 6, lane = tid & 63;
  const int wm = wid >> 1, wn = wid & 1;
  const int l15 = lane & 15, q = lane >> 4;

  if (tid < BM) srw[tid] = rw[(size_t)(m0 + tid) * NE + e];

  const float* w1e = w1 + (size_t)e * ND * (2 * NF);

  floatx4 accG[4][2], accU[4][2];
#pragma unroll
  for (int i = 0; i < 4; i++)
#pragma unroll
    for (int j = 0; j < 2; j++) {
      accG[i][j] = (floatx4){0.f, 0.f, 0.f, 0.f};
      accU[i][j] = (floatx4){0.f, 0.f, 0.f, 0.f};
    }

  // A staging: wave stages rows [wid*32, wid*32+32), 2 x global_load_lds(16B)
  const int arow = wid * 32 + (lane >> 2);
  const int akoff = (lane & 3) * 8;
  const unsigned short* aptr = xb + (size_t)(m0 + arow) * ND + akoff;
  unsigned short* aLds = &sA[wid * 32 * BK];  // wave-uniform

  // B staging: wave handles k-group [wid*8, wid*8+8), lane = column
  const float* gptr0 = w1e + (size_t)(wid * 8) * (2 * NF) + n0 + lane;

  for (int kb = 0; kb < ND / BK; ++kb) {
    const unsigned short* ap = aptr + kb * BK;
    const float* gp = gptr0 + (size_t)kb * BK * (2 * NF);
    float gv[8], uv[8];
#pragma unroll
    for (int r = 0; r < 8; r++) {
      gv[r] = gp[(size_t)r * (2 * NF)];
      uv[r] = gp[(size_t)r * (2 * NF) + NF];
    }

    __syncthreads();  // prior iteration's LDS reads done

    GLOAD_LDS16(ap, aLds);
    GLOAD_LDS16(ap + 16 * ND, aLds + 16 * BK);

    uint4 wg, wu;
    wg.x = pk_bf16(gv[0], gv[1]); wg.y = pk_bf16(gv[2], gv[3]);
    wg.z = pk_bf16(gv[4], gv[5]); wg.w = pk_bf16(gv[6], gv[7]);
    wu.x = pk_bf16(uv[0], uv[1]); wu.y = pk_bf16(uv[2], uv[3]);
    wu.z = pk_bf16(uv[4], uv[5]); wu.w = pk_bf16(uv[6], uv[7]);
    *((uint4*)&sG[lane * BSTR + wid * 8]) = wg;
    *((uint4*)&sU[lane * BSTR + wid * 8]) = wu;

    __syncthreads();  // staging visible

    short8 bg0 = *(const short8*)&sG[(wn * 32 + 0  + l15) * BSTR + q * 8];
    short8 bg1 = *(const short8*)&sG[(wn * 32 + 16 + l15) * BSTR + q * 8];
    short8 bu0 = *(const short8*)&sU[(wn * 32 + 0  + l15) * BSTR + q * 8];
    short8 bu1 = *(const short8*)&sU[(wn * 32 + 16 + l15) * BSTR + q * 8];
#pragma unroll
    for (int i = 0; i < 4; i++) {
      short8 af = *(const short8*)&sA[(wm * 64 + i * 16 + l15) * BK + q * 8];
      accG[i][0] = __builtin_amdgcn_mfma_f32_16x16x32_bf16(af, bg0, accG[i][0], 0, 0, 0);
      accG[i][1] = __builtin_amdgcn_mfma_f32_16x16x32_bf16(af, bg1, accG[i][1], 0, 0, 0);
      accU[i][0] = __builtin_amdgcn_mfma_f32_16x16x32_bf16(af, bu0, accU[i][0], 0, 0, 0);
      accU[i][1] = __builtin_amdgcn_mfma_f32_16x16x32_bf16(af, bu1, accU[i][1], 0, 0, 0);
    }
  }

  // Epilogue: gated' = up * silu(gate) * rw, store bf16
  const size_t obase = (size_t)m0 * NEF + (size_t)e * NF + n0 + wn * 32;
#pragma unroll
  for (int i = 0; i < 4; i++)
#pragma unroll
    for (int j = 0; j < 2; j++)
#pragma unroll
      for (int r = 0; r < 4; r++) {
        int row = wm * 64 + i * 16 + q * 4 + r;
        float g = accG[i][j][r];
        float u = accU[i][j][r];
        float sig = __builtin_amdgcn_rcpf(1.f + __expf(-g));
        float val = u * g * sig * srw[row];
        gws[obase + (size_t)row * NEF + j * 16 + l15] = bf16_1(val);
      }
}

// ------------------------------------------- Phase B: gated' @ W2 -> output
// grid: (16 mtiles * 32 ntiles, KSPLIT), 256 threads.
// K-split x4: each block covers 6144 of K (= 8 experts), fp32 atomicAdd
// epilogue into zero-initialized out. 2048 blocks = 8 blocks/CU.
__global__ __launch_bounds__(256, 2) void k_gemm2(
    const unsigned short* __restrict__ gb,  // NT x NEF bf16
    const float* __restrict__ w2,           // NEF x ND fp32 ((E,F,D) flattened)
    float* __restrict__ out)                // NT x ND fp32 (pre-zeroed)
{
  __shared__ unsigned short sA[BM * BK];
  __shared__ unsigned short sB[BN * BSTR];

  const int mt = blockIdx.x & 15;
  const int nt = blockIdx.x >> 4;   // 0..31
  const int m0 = mt * BM, n0 = nt * BN;
  const int tid = threadIdx.x;
  const int wid = tid >> 6, lane = tid & 63;
  const int wm = wid >> 1, wn = wid & 1;
  const int l15 = lane & 15, q = lane >> 4;

  const int kb0 = blockIdx.y * (NEF / BK / KSPLIT);  // 192 iters per split
  const int kb1 = kb0 + (NEF / BK / KSPLIT);

  floatx4 acc[4][2];
#pragma unroll
  for (int i = 0; i < 4; i++)
#pragma unroll
    for (int j = 0; j < 2; j++) acc[i][j] = (floatx4){0.f, 0.f, 0.f, 0.f};

  const int arow = wid * 32 + (lane >> 2);
  const int akoff = (lane & 3) * 8;
  const unsigned short* aptr = gb + (size_t)(m0 + arow) * NEF + akoff;
  unsigned short* aLds = &sA[wid * 32 * BK];

  const float* bptr0 = w2 + (size_t)(wid * 8) * ND + n0 + lane;

  for (int kb = kb0; kb < kb1; ++kb) {
    const unsigned short* ap = aptr + kb * BK;
    const float* bp = bptr0 + (size_t)kb * BK * ND;
    float bv[8];
#pragma unroll
    for (int r = 0; r < 8; r++) bv[r] = bp[(size_t)r * ND];

    __syncthreads();

    GLOAD_LDS16(ap, aLds);
    GLOAD_LDS16(ap + 16 * NEF, aLds + 16 * BK);

    uint4 wb;
    wb.x = pk_bf16(bv[0], bv[1]); wb.y = pk_bf16(bv[2], bv[3]);
    wb.z = pk_bf16(bv[4], bv[5]); wb.w = pk_bf16(bv[6], bv[7]);
    *((uint4*)&sB[lane * BSTR + wid * 8]) = wb;

    __syncthreads();

    short8 b0 = *(const short8*)&sB[(wn * 32 + 0  + l15) * BSTR + q * 8];
    short8 b1 = *(const short8*)&sB[(wn * 32 + 16 + l15) * BSTR + q * 8];
#pragma unroll
    for (int i = 0; i < 4; i++) {
      short8 af = *(const short8*)&sA[(wm * 64 + i * 16 + l15) * BK + q * 8];
      acc[i][0] = __builtin_amdgcn_mfma_f32_16x16x32_bf16(af, b0, acc[i][0], 0, 0, 0);
      acc[i][1] = __builtin_amdgcn_mfma_f32_16x16x32_bf16(af, b1, acc[i][1], 0, 0, 0);
    }
  }

  // fp32 atomic accumulate (4 contributions per element, pre-zeroed out)
#pragma unroll
  for (int i = 0; i < 4; i++)
#pragma unroll
    for (int j = 0; j < 2; j++)
#pragma unroll
      for (int r = 0; r < 4; r++) {
        int row = wm * 64 + i * 16 + q * 4 + r;
        unsafeAtomicAdd(&out[(size_t)(m0 + row) * ND + n0 + wn * 32 + j * 16 + l15],
                        acc[i][j][r]);
      }
}

// ---------------------------------------------------------------------------
extern "C" void kernel_launch(void* const* d_in, const int* in_sizes, int n_in,
                              void* d_out, int out_size, void* d_ws, size_t ws_size,
                              hipStream_t stream) {
  const float* x  = (const float*)d_in[0];   // hidden_states (T,D)
  const float* rw = (const float*)d_in[1];   // routing_weights (T,E)
  // d_in[2] router_indices: unused by reference
  const float* w1 = (const float*)d_in[3];   // gate_up_proj (E,D,2F)
  const float* w2 = (const float*)d_in[4];   // down_proj (E,F,D)
  float* out = (float*)d_out;

  unsigned short* xb = (unsigned short*)d_ws;          // NT*ND bf16 (8 MB)
  unsigned short* gb = xb + (size_t)NT * ND;           // NT*NEF bf16 (100.7 MB)

  hipMemsetAsync(out, 0, (size_t)out_size * sizeof(float), stream);

  k_cvt_x<<<(NT * ND / 4 + 255) / 256, 256, 0, stream>>>(x, xb, NT * ND / 4);

  dim3 gA(16 * (NF / BN), NE);  // 192 x 32
  k_gemm1<<<gA, 256, 0, stream>>>(xb, w1, rw, gb);

  dim3 gB(16 * (ND / BN), KSPLIT);  // 512 x 4 = 2048 blocks
  k_gemm2<<<gB, 256, 0, stream>>>(gb, w2, out);
}

// Round 3
// 1552.746 us; speedup vs baseline: 1.2144x; 1.0784x over previous
//
#include <hip/hip_runtime.h>
#include <stdint.h>

// Problem constants (dense MoE: router_indices UNUSED by the reference)
#define NE 32
#define ND 2048
#define NF 768
#define NF2 1536        // 2F
#define NT 2048
#define NEF (NE * NF)   // 24576
#define KH 12288        // W2 K-half

// Tile config
#define BM 128
#define BN 64
#define BK 32
#define BSTR 40     // legacy-path LDS B stride

typedef __attribute__((ext_vector_type(8))) short short8;
typedef __attribute__((ext_vector_type(4))) float floatx4;

__device__ __forceinline__ unsigned pk_bf16(float a, float b) {
  union { float f; unsigned u; } ua, ub;
  ua.f = a; ub.f = b;
  unsigned ra = (ua.u + 0x7fffu + ((ua.u >> 16) & 1u)) >> 16;
  unsigned rb = (ub.u + 0x7fffu + ((ub.u >> 16) & 1u)) & 0xffff0000u;
  return ra | rb;
}
__device__ __forceinline__ unsigned short bf16_1(float a) {
  union { float f; unsigned u; } ua; ua.f = a;
  return (unsigned short)((ua.u + 0x7fffu + ((ua.u >> 16) & 1u)) >> 16);
}

#define GLOAD_LDS16(g, l)                                                     \
  __builtin_amdgcn_global_load_lds(                                           \
      (const __attribute__((address_space(1))) void*)(g),                     \
      (__attribute__((address_space(3))) void*)(l), 16, 0, 0)

// ---------------------------------------------------------------- X -> bf16
__global__ void k_cvt_x(const float* __restrict__ x, unsigned short* __restrict__ xb, int n4) {
  int i = blockIdx.x * blockDim.x + threadIdx.x;
  if (i < n4) {
    float4 v = ((const float4*)x)[i];
    uint2 o;
    o.x = pk_bf16(v.x, v.y);
    o.y = pk_bf16(v.z, v.w);
    ((uint2*)xb)[i] = o;
  }
}

// ------------------------------------ fp32 [R][C] -> bf16 [C][R] transpose
// 64x64 tile, 256 threads. blockIdx.z selects sub-matrix (stride zstride elems
// on both sides -- in/out have equal element counts).
__global__ void k_trans(const float* __restrict__ in, unsigned short* __restrict__ out,
                        int R, int C, size_t zstride) {
  __shared__ float sT[64][65];
  in  += (size_t)blockIdx.z * zstride;
  out += (size_t)blockIdx.z * zstride;
  const int r0 = blockIdx.y * 64, c0 = blockIdx.x * 64;
  const int t = threadIdx.x;
  const int lrow = t >> 4, lc4 = (t & 15) * 4;
#pragma unroll
  for (int i = 0; i < 4; i++) {
    float4 v = *(const float4*)&in[(size_t)(r0 + lrow + i * 16) * C + c0 + lc4];
    sT[lrow + i * 16][lc4 + 0] = v.x;
    sT[lrow + i * 16][lc4 + 1] = v.y;
    sT[lrow + i * 16][lc4 + 2] = v.z;
    sT[lrow + i * 16][lc4 + 3] = v.w;
  }
  __syncthreads();
  const int c = t >> 2, rg = (t & 3) * 16;
  uint4 o0, o1;
  o0.x = pk_bf16(sT[rg + 0][c],  sT[rg + 1][c]);
  o0.y = pk_bf16(sT[rg + 2][c],  sT[rg + 3][c]);
  o0.z = pk_bf16(sT[rg + 4][c],  sT[rg + 5][c]);
  o0.w = pk_bf16(sT[rg + 6][c],  sT[rg + 7][c]);
  o1.x = pk_bf16(sT[rg + 8][c],  sT[rg + 9][c]);
  o1.y = pk_bf16(sT[rg + 10][c], sT[rg + 11][c]);
  o1.z = pk_bf16(sT[rg + 12][c], sT[rg + 13][c]);
  o1.w = pk_bf16(sT[rg + 14][c], sT[rg + 15][c]);
  unsigned short* op = &out[(size_t)(c0 + c) * R + r0 + rg];
  ((uint4*)op)[0] = o0;
  ((uint4*)op)[1] = o1;
}

// ---------------------- Phase A (bf16 path): X @ W1t + silu-gate -> gated'
// w1t: 8 experts, each [NF2][ND] bf16 (gate rows 0..NF-1, up rows NF..NF2-1)
// grid: (16 mtiles * 12 ntiles, 8 experts), 256 threads
__global__ __launch_bounds__(256, 2) void k_gemm1b(
    const unsigned short* __restrict__ xb,   // NT x ND bf16
    const unsigned short* __restrict__ w1t,  // 8 x NF2 x ND bf16
    const float* __restrict__ rw,            // NT x NE fp32
    unsigned short* __restrict__ gws,        // NT x NEF bf16
    int e0)
{
  __shared__ unsigned short sA[BM * BK];   // [m][k], 64B rows
  __shared__ unsigned short sG[BN * BK];   // [n][k]
  __shared__ unsigned short sU[BN * BK];
  __shared__ float srw[BM];

  const int el  = blockIdx.y;             // local expert 0..7
  const int e   = e0 + el;
  const int mt  = blockIdx.x & 15;        // mtile fastest -> W1-tile sharers adjacent
  const int nt  = blockIdx.x >> 4;        // 0..11
  const int m0  = mt * BM, n0 = nt * BN;
  const int tid = threadIdx.x;
  const int wid = tid >> 6, lane = tid & 63;
  const int wm = wid >> 1, wn = wid & 1;
  const int l15 = lane & 15, q = lane >> 4;

  if (tid < BM) srw[tid] = rw[(size_t)(m0 + tid) * NE + e];

  floatx4 accG[4][2], accU[4][2];
#pragma unroll
  for (int i = 0; i < 4; i++)
#pragma unroll
    for (int j = 0; j < 2; j++) {
      accG[i][j] = (floatx4){0.f, 0.f, 0.f, 0.f};
      accU[i][j] = (floatx4){0.f, 0.f, 0.f, 0.f};
    }

  const unsigned short* w1e = w1t + (size_t)el * NF2 * ND;

  // A staging: wave stages rows [wid*32, wid*32+32), 2 x glds16
  const int koff = (lane & 3) * 8;
  const unsigned short* aptr = xb + (size_t)(m0 + wid * 32 + (lane >> 2)) * ND + koff;
  unsigned short* aLds = &sA[wid * 32 * BK];
  // G/U staging: wave stages rows [wid*16, wid*16+16), 1 x glds16 each
  const unsigned short* gptr = w1e + (size_t)(n0 + wid * 16 + (lane >> 2)) * ND + koff;
  const unsigned short* uptr = gptr + (size_t)NF * ND;
  unsigned short* gLds = &sG[wid * 16 * BK];
  unsigned short* uLds = &sU[wid * 16 * BK];

  for (int kb = 0; kb < ND / BK; ++kb) {
    __syncthreads();  // prior iteration's LDS reads done
    GLOAD_LDS16(aptr + kb * BK, aLds);
    GLOAD_LDS16(aptr + kb * BK + 16 * ND, aLds + 16 * BK);
    GLOAD_LDS16(gptr + kb * BK, gLds);
    GLOAD_LDS16(uptr + kb * BK, uLds);
    __syncthreads();  // staging visible (barrier drains vmcnt)

    short8 bg0 = *(const short8*)&sG[(wn * 32 + 0  + l15) * BK + q * 8];
    short8 bg1 = *(const short8*)&sG[(wn * 32 + 16 + l15) * BK + q * 8];
    short8 bu0 = *(const short8*)&sU[(wn * 32 + 0  + l15) * BK + q * 8];
    short8 bu1 = *(const short8*)&sU[(wn * 32 + 16 + l15) * BK + q * 8];
#pragma unroll
    for (int i = 0; i < 4; i++) {
      short8 af = *(const short8*)&sA[(wm * 64 + i * 16 + l15) * BK + q * 8];
      accG[i][0] = __builtin_amdgcn_mfma_f32_16x16x32_bf16(af, bg0, accG[i][0], 0, 0, 0);
      accG[i][1] = __builtin_amdgcn_mfma_f32_16x16x32_bf16(af, bg1, accG[i][1], 0, 0, 0);
      accU[i][0] = __builtin_amdgcn_mfma_f32_16x16x32_bf16(af, bu0, accU[i][0], 0, 0, 0);
      accU[i][1] = __builtin_amdgcn_mfma_f32_16x16x32_bf16(af, bu1, accU[i][1], 0, 0, 0);
    }
  }

  // Epilogue: gated' = up * silu(gate) * rw, store bf16
  const size_t obase = (size_t)m0 * NEF + (size_t)e * NF + n0 + wn * 32;
#pragma unroll
  for (int i = 0; i < 4; i++)
#pragma unroll
    for (int j = 0; j < 2; j++)
#pragma unroll
      for (int r = 0; r < 4; r++) {
        int row = wm * 64 + i * 16 + q * 4 + r;
        float g = accG[i][j][r];
        float u = accU[i][j][r];
        float sig = __builtin_amdgcn_rcpf(1.f + __expf(-g));
        float val = u * g * sig * srw[row];
        gws[obase + (size_t)row * NEF + j * 16 + l15] = bf16_1(val);
      }
}

// ---------------------- Phase B (bf16 path): gated' @ W2t -> out (atomic)
// w2t: [ND][KH] bf16 slab (one K-half of W2, transposed)
// grid: (16 mtiles * 32 ntiles, 2 ksplits), 256 threads
__global__ __launch_bounds__(256, 2) void k_gemm2b(
    const unsigned short* __restrict__ gb,   // NT x NEF bf16
    const unsigned short* __restrict__ w2t,  // ND x KH bf16
    float* __restrict__ out,                 // NT x ND fp32 (pre-zeroed)
    int kbase)                               // global k offset of this slab
{
  __shared__ unsigned short sA[BM * BK];
  __shared__ unsigned short sB[BN * BK];

  const int mt = blockIdx.x & 15;
  const int nt = blockIdx.x >> 4;   // 0..31
  const int m0 = mt * BM, n0 = nt * BN;
  const int tid = threadIdx.x;
  const int wid = tid >> 6, lane = tid & 63;
  const int wm = wid >> 1, wn = wid & 1;
  const int l15 = lane & 15, q = lane >> 4;

  const int kb0 = blockIdx.y * (KH / BK / 2);  // 192 iters per block
  const int kb1 = kb0 + (KH / BK / 2);

  floatx4 acc[4][2];
#pragma unroll
  for (int i = 0; i < 4; i++)
#pragma unroll
    for (int j = 0; j < 2; j++) acc[i][j] = (floatx4){0.f, 0.f, 0.f, 0.f};

  const int koff = (lane & 3) * 8;
  const unsigned short* aptr = gb + (size_t)(m0 + wid * 32 + (lane >> 2)) * NEF + kbase + koff;
  unsigned short* aLds = &sA[wid * 32 * BK];
  const unsigned short* bptr = w2t + (size_t)(n0 + wid * 16 + (lane >> 2)) * KH + koff;
  unsigned short* bLds = &sB[wid * 16 * BK];

  for (int kb = kb0; kb < kb1; ++kb) {
    __syncthreads();
    GLOAD_LDS16(aptr + kb * BK, aLds);
    GLOAD_LDS16(aptr + kb * BK + 16 * NEF, aLds + 16 * BK);
    GLOAD_LDS16(bptr + kb * BK, bLds);
    __syncthreads();

    short8 b0 = *(const short8*)&sB[(wn * 32 + 0  + l15) * BK + q * 8];
    short8 b1 = *(const short8*)&sB[(wn * 32 + 16 + l15) * BK + q * 8];
#pragma unroll
    for (int i = 0; i < 4; i++) {
      short8 af = *(const short8*)&sA[(wm * 64 + i * 16 + l15) * BK + q * 8];
      acc[i][0] = __builtin_amdgcn_mfma_f32_16x16x32_bf16(af, b0, acc[i][0], 0, 0, 0);
      acc[i][1] = __builtin_amdgcn_mfma_f32_16x16x32_bf16(af, b1, acc[i][1], 0, 0, 0);
    }
  }

#pragma unroll
  for (int i = 0; i < 4; i++)
#pragma unroll
    for (int j = 0; j < 2; j++)
#pragma unroll
      for (int r = 0; r < 4; r++) {
        int row = wm * 64 + i * 16 + q * 4 + r;
        unsafeAtomicAdd(&out[(size_t)(m0 + row) * ND + n0 + wn * 32 + j * 16 + l15],
                        acc[i][j][r]);
      }
}

// ======================= legacy fp32-weight path (ws fallback) =============
__global__ __launch_bounds__(256, 2) void k_gemm1_legacy(
    const unsigned short* __restrict__ xb, const float* __restrict__ w1,
    const float* __restrict__ rw, unsigned short* __restrict__ gws)
{
  __shared__ unsigned short sA[BM * BK];
  __shared__ unsigned short sG[BN * BSTR];
  __shared__ unsigned short sU[BN * BSTR];
  __shared__ float srw[BM];
  const int e = blockIdx.y, mt = blockIdx.x & 15, nt = blockIdx.x >> 4;
  const int m0 = mt * BM, n0 = nt * BN;
  const int tid = threadIdx.x, wid = tid >> 6, lane = tid & 63;
  const int wm = wid >> 1, wn = wid & 1, l15 = lane & 15, q = lane >> 4;
  if (tid < BM) srw[tid] = rw[(size_t)(m0 + tid) * NE + e];
  const float* w1e = w1 + (size_t)e * ND * (2 * NF);
  floatx4 accG[4][2], accU[4][2];
#pragma unroll
  for (int i = 0; i < 4; i++)
#pragma unroll
    for (int j = 0; j < 2; j++) {
      accG[i][j] = (floatx4){0.f, 0.f, 0.f, 0.f};
      accU[i][j] = (floatx4){0.f, 0.f, 0.f, 0.f};
    }
  const int arow = wid * 32 + (lane >> 2), akoff = (lane & 3) * 8;
  const unsigned short* aptr = xb + (size_t)(m0 + arow) * ND + akoff;
  unsigned short* aLds = &sA[wid * 32 * BK];
  const float* gptr0 = w1e + (size_t)(wid * 8) * (2 * NF) + n0 + lane;
  for (int kb = 0; kb < ND / BK; ++kb) {
    const float* gp = gptr0 + (size_t)kb * BK * (2 * NF);
    float gv[8], uv[8];
#pragma unroll
    for (int r = 0; r < 8; r++) {
      gv[r] = gp[(size_t)r * (2 * NF)];
      uv[r] = gp[(size_t)r * (2 * NF) + NF];
    }
    __syncthreads();
    GLOAD_LDS16(aptr + kb * BK, aLds);
    GLOAD_LDS16(aptr + kb * BK + 16 * ND, aLds + 16 * BK);
    uint4 wg, wu;
    wg.x = pk_bf16(gv[0], gv[1]); wg.y = pk_bf16(gv[2], gv[3]);
    wg.z = pk_bf16(gv[4], gv[5]); wg.w = pk_bf16(gv[6], gv[7]);
    wu.x = pk_bf16(uv[0], uv[1]); wu.y = pk_bf16(uv[2], uv[3]);
    wu.z = pk_bf16(uv[4], uv[5]); wu.w = pk_bf16(uv[6], uv[7]);
    *((uint4*)&sG[lane * BSTR + wid * 8]) = wg;
    *((uint4*)&sU[lane * BSTR + wid * 8]) = wu;
    __syncthreads();
    short8 bg0 = *(const short8*)&sG[(wn * 32 + 0  + l15) * BSTR + q * 8];
    short8 bg1 = *(const short8*)&sG[(wn * 32 + 16 + l15) * BSTR + q * 8];
    short8 bu0 = *(const short8*)&sU[(wn * 32 + 0  + l15) * BSTR + q * 8];
    short8 bu1 = *(const short8*)&sU[(wn * 32 + 16 + l15) * BSTR + q * 8];
#pragma unroll
    for (int i = 0; i < 4; i++) {
      short8 af = *(const short8*)&sA[(wm * 64 + i * 16 + l15) * BK + q * 8];
      accG[i][0] = __builtin_amdgcn_mfma_f32_16x16x32_bf16(af, bg0, accG[i][0], 0, 0, 0);
      accG[i][1] = __builtin_amdgcn_mfma_f32_16x16x32_bf16(af, bg1, accG[i][1], 0, 0, 0);
      accU[i][0] = __builtin_amdgcn_mfma_f32_16x16x32_bf16(af, bu0, accU[i][0], 0, 0, 0);
      accU[i][1] = __builtin_amdgcn_mfma_f32_16x16x32_bf16(af, bu1, accU[i][1], 0, 0, 0);
    }
  }
  const size_t obase = (size_t)m0 * NEF + (size_t)e * NF + n0 + wn * 32;
#pragma unroll
  for (int i = 0; i < 4; i++)
#pragma unroll
    for (int j = 0; j < 2; j++)
#pragma unroll
      for (int r = 0; r < 4; r++) {
        int row = wm * 64 + i * 16 + q * 4 + r;
        float g = accG[i][j][r], u = accU[i][j][r];
        float sig = __builtin_amdgcn_rcpf(1.f + __expf(-g));
        gws[obase + (size_t)row * NEF + j * 16 + l15] = bf16_1(u * g * sig * srw[row]);
      }
}

__global__ __launch_bounds__(256, 2) void k_gemm2_legacy(
    const unsigned short* __restrict__ gb, const float* __restrict__ w2,
    float* __restrict__ out)
{
  __shared__ unsigned short sA[BM * BK];
  __shared__ unsigned short sB[BN * BSTR];
  const int mt = blockIdx.x & 15, nt = blockIdx.x >> 4;
  const int m0 = mt * BM, n0 = nt * BN;
  const int tid = threadIdx.x, wid = tid >> 6, lane = tid & 63;
  const int wm = wid >> 1, wn = wid & 1, l15 = lane & 15, q = lane >> 4;
  const int kb0 = blockIdx.y * (NEF / BK / 4), kb1 = kb0 + (NEF / BK / 4);
  floatx4 acc[4][2];
#pragma unroll
  for (int i = 0; i < 4; i++)
#pragma unroll
    for (int j = 0; j < 2; j++) acc[i][j] = (floatx4){0.f, 0.f, 0.f, 0.f};
  const int arow = wid * 32 + (lane >> 2), akoff = (lane & 3) * 8;
  const unsigned short* aptr = gb + (size_t)(m0 + arow) * NEF + akoff;
  unsigned short* aLds = &sA[wid * 32 * BK];
  const float* bptr0 = w2 + (size_t)(wid * 8) * ND + n0 + lane;
  for (int kb = kb0; kb < kb1; ++kb) {
    const float* bp = bptr0 + (size_t)kb * BK * ND;
    float bv[8];
#pragma unroll
    for (int r = 0; r < 8; r++) bv[r] = bp[(size_t)r * ND];
    __syncthreads();
    GLOAD_LDS16(aptr + kb * BK, aLds);
    GLOAD_LDS16(aptr + kb * BK + 16 * NEF, aLds + 16 * BK);
    uint4 wb;
    wb.x = pk_bf16(bv[0], bv[1]); wb.y = pk_bf16(bv[2], bv[3]);
    wb.z = pk_bf16(bv[4], bv[5]); wb.w = pk_bf16(bv[6], bv[7]);
    *((uint4*)&sB[lane * BSTR + wid * 8]) = wb;
    __syncthreads();
    short8 b0 = *(const short8*)&sB[(wn * 32 + 0  + l15) * BSTR + q * 8];
    short8 b1 = *(const short8*)&sB[(wn * 32 + 16 + l15) * BSTR + q * 8];
#pragma unroll
    for (int i = 0; i < 4; i++) {
      short8 af = *(const short8*)&sA[(wm * 64 + i * 16 + l15) * BK + q * 8];
      acc[i][0] = __builtin_amdgcn_mfma_f32_16x16x32_bf16(af, b0, acc[i][0], 0, 0, 0);
      acc[i][1] = __builtin_amdgcn_mfma_f32_16x16x32_bf16(af, b1, acc[i][1], 0, 0, 0);
    }
  }
#pragma unroll
  for (int i = 0; i < 4; i++)
#pragma unroll
    for (int j = 0; j < 2; j++)
#pragma unroll
      for (int r = 0; r < 4; r++) {
        int row = wm * 64 + i * 16 + q * 4 + r;
        unsafeAtomicAdd(&out[(size_t)(m0 + row) * ND + n0 + wn * 32 + j * 16 + l15],
                        acc[i][j][r]);
      }
}

// ---------------------------------------------------------------------------
extern "C" void kernel_launch(void* const* d_in, const int* in_sizes, int n_in,
                              void* d_out, int out_size, void* d_ws, size_t ws_size,
                              hipStream_t stream) {
  const float* x  = (const float*)d_in[0];   // hidden_states (T,D)
  const float* rw = (const float*)d_in[1];   // routing_weights (T,E)
  // d_in[2] router_indices: unused by reference
  const float* w1 = (const float*)d_in[3];   // gate_up_proj (E,D,2F)
  const float* w2 = (const float*)d_in[4];   // down_proj (E,F,D)
  float* out = (float*)d_out;

  // ws layout: [xb 8MB][gb 100.7MB][wtb 50.3MB]
  unsigned short* xb  = (unsigned short*)d_ws;
  unsigned short* gb  = xb + (size_t)NT * ND;
  unsigned short* wtb = gb + (size_t)NT * NEF;
  const size_t WS_NEED = ((size_t)NT * ND + (size_t)NT * NEF +
                          (size_t)8 * NF2 * ND) * 2;  // 159.4 MB

  hipMemsetAsync(out, 0, (size_t)out_size * sizeof(float), stream);
  k_cvt_x<<<(NT * ND / 4 + 255) / 256, 256, 0, stream>>>(x, xb, NT * ND / 4);

  if (ws_size >= WS_NEED) {
    // bf16-transposed weight path
    for (int qc = 0; qc < 4; ++qc) {
      dim3 gt(NF2 / 64, ND / 64, 8);  // 24 x 32 x 8
      k_trans<<<gt, 256, 0, stream>>>(w1 + (size_t)qc * 8 * ND * NF2, wtb,
                                      ND, NF2, (size_t)ND * NF2);
      dim3 g1(16 * (NF / BN), 8);     // 192 x 8
      k_gemm1b<<<g1, 256, 0, stream>>>(xb, wtb, rw, gb, qc * 8);
    }
    for (int h = 0; h < 2; ++h) {
      dim3 gt(ND / 64, KH / 64, 1);   // 32 x 192
      k_trans<<<gt, 256, 0, stream>>>(w2 + (size_t)h * KH * ND, wtb, KH, ND, 0);
      dim3 g2(16 * (ND / BN), 2);     // 512 x 2
      k_gemm2b<<<g2, 256, 0, stream>>>(gb, wtb, out, h * KH);
    }
  } else {
    // legacy fp32-weight path (R2 structure)
    dim3 gA(16 * (NF / BN), NE);
    k_gemm1_legacy<<<gA, 256, 0, stream>>>(xb, w1, rw, gb);
    dim3 gB(16 * (ND / BN), 4);
    k_gemm2_legacy<<<gB, 256, 0, stream>>>(gb, w2, out);
  }
}